// Round 1
// baseline (321.733 us; speedup 1.0000x reference)
//
#include <hip/hip_runtime.h>
#include <hip/hip_bf16.h>

#define BB 8
#define NN 2048
#define EE 64
#define DD 256

typedef __attribute__((ext_vector_type(8))) short short8;
typedef __attribute__((ext_vector_type(4))) float f32x4;
typedef __attribute__((ext_vector_type(4))) unsigned short ushort4v;

#define MFMA16(a, b, c) __builtin_amdgcn_mfma_f32_16x16x32_bf16((a), (b), (c), 0, 0, 0)

__device__ inline void gload16(const void* g, void* l) {
  __builtin_amdgcn_global_load_lds(
      (const __attribute__((address_space(1))) unsigned int*)g,
      (__attribute__((address_space(3))) unsigned int*)l, 16, 0, 0);
}

__device__ inline float bf2f(unsigned short u) {
  union { unsigned int i; float f; } v;
  v.i = ((unsigned int)u) << 16;
  return v.f;
}
__device__ inline unsigned short f2bf(float f) {
  union { float f; unsigned int i; } v;
  v.f = f;
  unsigned int r = v.i + 0x7FFFu + ((v.i >> 16) & 1u);
  return (unsigned short)(r >> 16);
}

// ---------------------------------------------------------------------------
// Kernel P: combine weights, convert to bf16.
//   wqc = (mq_w @ wq_w) * SC (bf16), bqc = (mq_w @ wq_b + mq_b) * SC
//   wkc = (mk_w @ wk_w)      (bf16), bkc = (mk_w @ wk_b + mk_b)
//   wvc/outwb/ffnwb: bf16 copies. SC = log2(e)/8 folds softmax scale + exp2.
// ---------------------------------------------------------------------------
__global__ __launch_bounds__(128) void kprep(
    const float* __restrict__ wq_w, const float* __restrict__ wq_b,
    const float* __restrict__ wk_w, const float* __restrict__ wk_b,
    const float* __restrict__ wv_w, const float* __restrict__ mq_w,
    const float* __restrict__ mq_b, const float* __restrict__ mk_w,
    const float* __restrict__ mk_b, const float* __restrict__ out_w,
    const float* __restrict__ ffn_w,
    unsigned short* __restrict__ wqc, float* __restrict__ bqc,
    unsigned short* __restrict__ wkc, float* __restrict__ bkc,
    unsigned short* __restrict__ wvc, unsigned short* __restrict__ outwb,
    unsigned short* __restrict__ ffnwb) {
  const float SC = 0.18033688011112042f;  // log2(e)/8
  int o = blockIdx.x;   // 0..255 output row
  int t = threadIdx.x;  // 0..127
  if (t < 64) {
    float acc = 0.f;
#pragma unroll 4
    for (int d = 0; d < 256; d++) acc += mq_w[o * 256 + d] * wq_w[d * 64 + t];
    wqc[o * 64 + t] = f2bf(acc * SC);
  } else {
    int k = t - 64;
    float acc = 0.f;
#pragma unroll 4
    for (int d = 0; d < 256; d++) acc += mk_w[o * 256 + d] * wk_w[d * 64 + k];
    wkc[o * 64 + k] = f2bf(acc);
  }
  if (t == 0) {
    float acc = 0.f;
    for (int d = 0; d < 256; d++) acc += mq_w[o * 256 + d] * wq_b[d];
    bqc[o] = (acc + mq_b[o]) * SC;
  }
  if (t == 64) {
    float acc = 0.f;
    for (int d = 0; d < 256; d++) acc += mk_w[o * 256 + d] * wk_b[d];
    bkc[o] = acc + mk_b[o];
  }
  int gid = o * 128 + t;
  if (gid < 16384) {
    wvc[gid] = f2bf(wv_w[gid]);
    outwb[gid] = f2bf(out_w[gid]);
  }
  if (gid < 4096) ffnwb[gid] = f2bf(ffn_w[gid]);
}

// ---------------------------------------------------------------------------
// Kernel 1: LayerNorm + q/k projections (row-major bf16) + v projection
// written TRANSPOSED: vt[b][d][n] bf16. 4 waves x 16 rows per block.
// ---------------------------------------------------------------------------
__global__ __launch_bounds__(256) void kproj(
    const float* __restrict__ x, const float* __restrict__ ln_g,
    const float* __restrict__ ln_b, const unsigned short* __restrict__ wqc,
    const float* __restrict__ bqc, const unsigned short* __restrict__ wkc,
    const float* __restrict__ bkc, const unsigned short* __restrict__ wvc,
    const float* __restrict__ wv_b, unsigned short* __restrict__ qout,
    unsigned short* __restrict__ kout, unsigned short* __restrict__ vtout) {
  __shared__ __align__(1024) char lds[4 * 10240];
  int tid = threadIdx.x;
  int w = tid >> 6, l = tid & 63;
  int c = l & 15, g = l >> 4;
  int blk = blockIdx.x;
  int b = blk >> 5;
  int i0 = (blk & 31) * 64 + w * 16;  // row within batch
  size_t row0 = (size_t)b * NN + i0;
  char* xnb = lds + w * 10240;         // [16][64] bf16, xor-swizzled rows
  char* tlb = lds + w * 10240 + 2048;  // [16][256] bf16, xor-swizzled rows

  // ---- LayerNorm: 4 lanes per row, 16 cols each ----
  int rl = l >> 2;
  int cc = (l & 3) * 16;
  float xv[16];
  {
    const float* xr = x + (row0 + rl) * EE + cc;
#pragma unroll
    for (int i = 0; i < 4; i++) {
      float4 v = *(const float4*)(xr + i * 4);
      xv[i * 4 + 0] = v.x; xv[i * 4 + 1] = v.y;
      xv[i * 4 + 2] = v.z; xv[i * 4 + 3] = v.w;
    }
  }
  float s = 0.f, s2 = 0.f;
#pragma unroll
  for (int i = 0; i < 16; i++) { s += xv[i]; s2 += xv[i] * xv[i]; }
  s += __shfl_xor(s, 1); s += __shfl_xor(s, 2);
  s2 += __shfl_xor(s2, 1); s2 += __shfl_xor(s2, 2);
  float mean = s * (1.f / 64.f);
  float var = s2 * (1.f / 64.f) - mean * mean;
  float rstd = rsqrtf(var + 1e-5f);
  {
    int swzr = (rl & 7) << 4;
    unsigned short pk[16];
#pragma unroll
    for (int i = 0; i < 16; i++)
      pk[i] = f2bf((xv[i] - mean) * rstd * ln_g[cc + i] + ln_b[cc + i]);
#pragma unroll
    for (int hh = 0; hh < 2; hh++) {
      short8 d;
#pragma unroll
      for (int i = 0; i < 8; i++) d[i] = (short)pk[hh * 8 + i];
      *(short8*)(xnb + rl * 128 + (((l & 3) * 32 + hh * 16) ^ swzr)) = d;
    }
  }
  __syncthreads();

  // ---- A fragments from x_norm ----
  int swz = (c & 7) << 4;
  int o2_0 = (g * 16) ^ swz;
  int o2_1 = (64 + g * 16) ^ swz;
  short8 af0 = *(const short8*)(xnb + c * 128 + o2_0);
  short8 af1 = *(const short8*)(xnb + c * 128 + o2_1);

  // ---- q ----
#pragma unroll
  for (int dt = 0; dt < 16; dt++) {
    float bias = bqc[dt * 16 + c];
    f32x4 acc = {bias, bias, bias, bias};
    acc = MFMA16(af0, *(const short8*)(wqc + (dt * 16 + c) * 64 + g * 8), acc);
    acc = MFMA16(af1, *(const short8*)(wqc + (dt * 16 + c) * 64 + 32 + g * 8), acc);
#pragma unroll
    for (int r = 0; r < 4; r++) {
      int row = 4 * g + r;
      *(unsigned short*)(tlb + row * 512 + ((dt * 32 + 2 * c) ^ ((row & 7) << 4))) = f2bf(acc[r]);
    }
  }
  __syncthreads();
#pragma unroll
  for (int c2 = 0; c2 < 8; c2++) {
    int flat = c2 * 1024 + l * 16;
    int rowt = flat >> 9;
    int off = flat & 511;
    short8 d = *(const short8*)(tlb + rowt * 512 + (off ^ ((rowt & 7) << 4)));
    *(short8*)((char*)qout + (row0 + rowt) * 512 + off) = d;
  }
  __syncthreads();

  // ---- k ----
#pragma unroll
  for (int dt = 0; dt < 16; dt++) {
    float bias = bkc[dt * 16 + c];
    f32x4 acc = {bias, bias, bias, bias};
    acc = MFMA16(af0, *(const short8*)(wkc + (dt * 16 + c) * 64 + g * 8), acc);
    acc = MFMA16(af1, *(const short8*)(wkc + (dt * 16 + c) * 64 + 32 + g * 8), acc);
#pragma unroll
    for (int r = 0; r < 4; r++) {
      int row = 4 * g + r;
      *(unsigned short*)(tlb + row * 512 + ((dt * 32 + 2 * c) ^ ((row & 7) << 4))) = f2bf(acc[r]);
    }
  }
  __syncthreads();
#pragma unroll
  for (int c2 = 0; c2 < 8; c2++) {
    int flat = c2 * 1024 + l * 16;
    int rowt = flat >> 9;
    int off = flat & 511;
    short8 d = *(const short8*)(tlb + rowt * 512 + (off ^ ((rowt & 7) << 4)));
    *(short8*)((char*)kout + (row0 + rowt) * 512 + off) = d;
  }

  // ---- v (transposed store) ----
#pragma unroll
  for (int dt = 0; dt < 16; dt++) {
    float bias = wv_b[dt * 16 + c];
    f32x4 acc = {bias, bias, bias, bias};
    acc = MFMA16(af0, *(const short8*)(wvc + (dt * 16 + c) * 64 + g * 8), acc);
    acc = MFMA16(af1, *(const short8*)(wvc + (dt * 16 + c) * 64 + 32 + g * 8), acc);
    ushort4v pk;
#pragma unroll
    for (int r = 0; r < 4; r++) pk[r] = f2bf(acc[r]);
    *(ushort4v*)(vtout + ((size_t)b * 256 + dt * 16 + c) * NN + i0 + 4 * g) = pk;
  }
}

// ---------------------------------------------------------------------------
// Kernel 2 (pass 1): per-(b,h,row) online softmax stats m,l over a j-half.
// 8 waves x 16 rows per block; K tile [64][256] staged swizzled via
// global_load_lds.
// ---------------------------------------------------------------------------
__global__ __launch_bounds__(512, 2) void kpass1(
    const unsigned short* __restrict__ qb, const unsigned short* __restrict__ kb,
    const float* __restrict__ wts, float* __restrict__ mout,
    float* __restrict__ lout) {
  __shared__ __align__(1024) char ldsk[32768];
  int tid = threadIdx.x;
  int w = tid >> 6, l = tid & 63, c = l & 15, g = l >> 4;
  int bx = blockIdx.x;
  int b = bx >> 4, it = bx & 15;
  int y = blockIdx.y;
  int i0 = it * 128 + w * 16;
  short8 qf[8];
  {
    const unsigned short* qr = qb + ((size_t)b * NN + i0 + c) * DD;
#pragma unroll
    for (int s = 0; s < 8; s++) qf[s] = *(const short8*)(qr + s * 32 + g * 8);
  }
  float m[16], ls[16];
#pragma unroll
  for (int i = 0; i < 16; i++) { m[i] = -1e30f; ls[i] = 0.f; }
  int swz = (c & 7) << 4;
  int o2_0 = (g * 16) ^ swz;
  int o2_1 = (64 + g * 16) ^ swz;
  const char* kb0 = ldsk + c * 512;

  for (int jt = 0; jt < 16; jt++) {
    int jb = y * 1024 + jt * 64;
    __syncthreads();
#pragma unroll
    for (int call = 0; call < 4; call++) {
      int chunk = call * 512 + tid;
      int j = chunk >> 5;
      int q16 = (chunk & 31) << 4;
      const char* src = (const char*)(kb + ((size_t)b * NN + jb + j) * DD) + (q16 ^ ((j & 7) << 4));
      gload16(src, ldsk + (chunk & ~63) * 16);
    }
    __syncthreads();
    float wj[4];
#pragma unroll
    for (int js = 0; js < 4; js++) wj[js] = wts[(size_t)b * NN + jb + js * 16 + c];
#pragma unroll
    for (int h = 0; h < 4; h++) {
      float sc[4][4];
#pragma unroll
      for (int js = 0; js < 4; js++) {
        f32x4 s4 = {0.f, 0.f, 0.f, 0.f};
        s4 = MFMA16(qf[2 * h], *(const short8*)(kb0 + js * 8192 + h * 128 + o2_0), s4);
        s4 = MFMA16(qf[2 * h + 1], *(const short8*)(kb0 + js * 8192 + h * 128 + o2_1), s4);
#pragma unroll
        for (int r = 0; r < 4; r++) sc[js][r] = (wj[js] == 0.f) ? -1e9f : s4[r];
      }
#pragma unroll
      for (int r = 0; r < 4; r++) {
        float vmax = fmaxf(fmaxf(sc[0][r], sc[1][r]), fmaxf(sc[2][r], sc[3][r]));
        float mo = m[h * 4 + r];
        float mn = fmaxf(mo, vmax);
        float e = exp2f(sc[0][r] - mn) + exp2f(sc[1][r] - mn) +
                  exp2f(sc[2][r] - mn) + exp2f(sc[3][r] - mn);
        ls[h * 4 + r] = ls[h * 4 + r] * exp2f(mo - mn) + e;
        m[h * 4 + r] = mn;
      }
    }
  }
#pragma unroll
  for (int xm = 1; xm <= 8; xm <<= 1) {
#pragma unroll
    for (int i = 0; i < 16; i++) {
      float m2 = __shfl_xor(m[i], xm);
      float l2 = __shfl_xor(ls[i], xm);
      float mn = fmaxf(m[i], m2);
      ls[i] = ls[i] * exp2f(m[i] - mn) + l2 * exp2f(m2 - mn);
      m[i] = mn;
    }
  }
  if (c == 0) {
#pragma unroll
    for (int h = 0; h < 4; h++)
#pragma unroll
      for (int r = 0; r < 4; r++) {
        size_t idx = (((size_t)y * BB + b) * 4 + h) * NN + i0 + 4 * g + r;
        mout[idx] = m[h * 4 + r];
        lout[idx] = ls[h * 4 + r];
      }
  }
}

// ---------------------------------------------------------------------------
// Kernel 3 (pass 2): recompute scores, a_j = w_j * sum_h exp2(s - c_h),
// accumulate num += a @ V (via P tile in LDS), plus row sums t.
// ---------------------------------------------------------------------------
__global__ __launch_bounds__(512, 2) void kpass2(
    const unsigned short* __restrict__ qb, const unsigned short* __restrict__ kb,
    const unsigned short* __restrict__ vt, const float* __restrict__ wts,
    const float* __restrict__ min_, const float* __restrict__ lin_,
    unsigned short* __restrict__ num, float* __restrict__ tout) {
  __shared__ __align__(1024) char lds[16384 + 16384 + 10240];
  int tid = threadIdx.x;
  int w = tid >> 6, l = tid & 63, c = l & 15, g = l >> 4;
  char* ldsk = lds;
  char* ldsv = lds + 16384;
  char* ldsp = lds + 32768 + w * 1280;  // per-wave P tile [16][40] bf16
  int bx = blockIdx.x;
  int b = bx >> 4, it = bx & 15;
  int y = blockIdx.y;
  int i0 = it * 128 + w * 16;

  float ch[16];
#pragma unroll
  for (int h = 0; h < 4; h++)
#pragma unroll
    for (int r = 0; r < 4; r++) {
      size_t ia = (((size_t)0 * BB + b) * 4 + h) * NN + i0 + 4 * g + r;
      size_t ib = (((size_t)1 * BB + b) * 4 + h) * NN + i0 + 4 * g + r;
      float ma = min_[ia], la = lin_[ia];
      float mb2 = min_[ib], lb = lin_[ib];
      float mm = fmaxf(ma, mb2);
      float ll = la * exp2f(ma - mm) + lb * exp2f(mb2 - mm);
      ch[h * 4 + r] = mm + log2f(ll);
    }

  short8 qf[8];
  {
    const unsigned short* qr = qb + ((size_t)b * NN + i0 + c) * DD;
#pragma unroll
    for (int s = 0; s < 8; s++) qf[s] = *(const short8*)(qr + s * 32 + g * 8);
  }
  f32x4 acc[16];
#pragma unroll
  for (int i = 0; i < 16; i++) acc[i] = (f32x4){0.f, 0.f, 0.f, 0.f};
  float tacc[4] = {0.f, 0.f, 0.f, 0.f};
  int swz = (c & 7) << 4;
  int o2_0 = (g * 16) ^ swz;
  int o2_1 = (64 + g * 16) ^ swz;
  const char* kb0 = ldsk + c * 512;
  const char* vb0 = ldsv + c * 64;
  int pw[8];
#pragma unroll
  for (int js = 0; js < 2; js++)
#pragma unroll
    for (int r = 0; r < 4; r++) pw[js * 4 + r] = (4 * g + r) * 80 + js * 32 + 2 * c;
  const char* prd = ldsp + c * 80 + g * 16;

  for (int jt = 0; jt < 32; jt++) {
    int jb = y * 1024 + jt * 32;
    __syncthreads();
#pragma unroll
    for (int call = 0; call < 2; call++) {  // K tile [32][256], swizzled
      int chunk = call * 512 + tid;
      int j = chunk >> 5;
      int q16 = (chunk & 31) << 4;
      const char* src = (const char*)(kb + ((size_t)b * NN + jb + j) * DD) + (q16 ^ ((j & 7) << 4));
      gload16(src, ldsk + (chunk & ~63) * 16);
    }
#pragma unroll
    for (int call = 0; call < 2; call++) {  // V^T tile [256][32], linear
      int chunk = call * 512 + tid;
      int d = chunk >> 2;
      int q16 = (chunk & 3) << 4;
      const char* src = (const char*)(vt + ((size_t)b * 256 + d) * NN + jb) + q16;
      gload16(src, ldsv + (chunk & ~63) * 16);
    }
    __syncthreads();
    float wj[2];
#pragma unroll
    for (int js = 0; js < 2; js++) wj[js] = wts[(size_t)b * NN + jb + js * 16 + c];
    float av[2][4];
#pragma unroll
    for (int js = 0; js < 2; js++) {
#pragma unroll
      for (int r = 0; r < 4; r++) av[js][r] = 0.f;
#pragma unroll
      for (int h = 0; h < 4; h++) {
        f32x4 s4 = {0.f, 0.f, 0.f, 0.f};
        s4 = MFMA16(qf[2 * h], *(const short8*)(kb0 + js * 8192 + h * 128 + o2_0), s4);
        s4 = MFMA16(qf[2 * h + 1], *(const short8*)(kb0 + js * 8192 + h * 128 + o2_1), s4);
#pragma unroll
        for (int r = 0; r < 4; r++) av[js][r] += exp2f(s4[r] - ch[h * 4 + r]);
      }
#pragma unroll
      for (int r = 0; r < 4; r++) { av[js][r] *= wj[js]; tacc[r] += av[js][r]; }
    }
#pragma unroll
    for (int js = 0; js < 2; js++)
#pragma unroll
      for (int r = 0; r < 4; r++)
        *(unsigned short*)(ldsp + pw[js * 4 + r]) = f2bf(av[js][r]);
    asm volatile("s_waitcnt lgkmcnt(0)" ::: "memory");
    __builtin_amdgcn_sched_barrier(0);
    short8 pf = *(const short8*)prd;
#pragma unroll
    for (int dt = 0; dt < 16; dt++) {
      short8 vf = *(const short8*)(vb0 + dt * 1024 + g * 16);
      acc[dt] = MFMA16(pf, vf, acc[dt]);
    }
  }
#pragma unroll
  for (int xm = 1; xm <= 8; xm <<= 1)
#pragma unroll
    for (int r = 0; r < 4; r++) tacc[r] += __shfl_xor(tacc[r], xm);
#pragma unroll
  for (int dt = 0; dt < 16; dt++)
#pragma unroll
    for (int r = 0; r < 4; r++)
      num[(((size_t)y * BB + b) * NN + i0 + 4 * g + r) * DD + dt * 16 + c] = f2bf(acc[dt][r]);
  if (c == 0)
#pragma unroll
    for (int r = 0; r < 4; r++)
      tout[((size_t)y * BB + b) * NN + i0 + 4 * g + r] = tacc[r];
}

// ---------------------------------------------------------------------------
// Kernel 4: out1 = x + (num/t)@out_w^T + out_b; out2 = softplus(LN(out1)@ffn^T
// + ffn_b); out = LN(out1 + out2).
// ---------------------------------------------------------------------------
__global__ __launch_bounds__(256) void kfinal(
    const unsigned short* __restrict__ num, const float* __restrict__ tws,
    const float* __restrict__ x, const unsigned short* __restrict__ outwb,
    const float* __restrict__ out_b, const float* __restrict__ ln_g,
    const float* __restrict__ ln_b, const unsigned short* __restrict__ ffnwb,
    const float* __restrict__ ffn_b, float* __restrict__ out) {
  __shared__ __align__(1024) char lds[4 * 2304];
  int tid = threadIdx.x, w = tid >> 6, l = tid & 63, c = l & 15, g = l >> 4;
  int blk = blockIdx.x;
  int b = blk >> 5;
  int i0 = (blk & 31) * 64 + w * 16;
  char* hb = lds + w * 2304;  // [16][72] bf16 (144B rows)

  short8 af[8];
  {
    const unsigned short* p0 = num + (((size_t)0 * BB + b) * NN + i0 + c) * DD;
    const unsigned short* p1 = num + (((size_t)1 * BB + b) * NN + i0 + c) * DD;
#pragma unroll
    for (int s = 0; s < 8; s++) {
      short8 a0 = *(const short8*)(p0 + s * 32 + g * 8);
      short8 a1 = *(const short8*)(p1 + s * 32 + g * 8);
      short8 o;
#pragma unroll
      for (int t2 = 0; t2 < 8; t2++)
        o[t2] = (short)f2bf(bf2f((unsigned short)a0[t2]) + bf2f((unsigned short)a1[t2]));
      af[s] = o;
    }
  }
  float trow[4];
#pragma unroll
  for (int r = 0; r < 4; r++)
    trow[r] = tws[((size_t)0 * BB + b) * NN + i0 + 4 * g + r] +
              tws[((size_t)1 * BB + b) * NN + i0 + 4 * g + r];
  f32x4 acc[4];
#pragma unroll
  for (int ct = 0; ct < 4; ct++) {
    acc[ct] = (f32x4){0.f, 0.f, 0.f, 0.f};
#pragma unroll
    for (int s = 0; s < 8; s++)
      acc[ct] = MFMA16(af[s], *(const short8*)(outwb + (ct * 16 + c) * DD + s * 32 + g * 8), acc[ct]);
  }
  float gv[4], bvv[4], obv[4], fbv[4];
#pragma unroll
  for (int ct = 0; ct < 4; ct++) {
    gv[ct] = ln_g[ct * 16 + c]; bvv[ct] = ln_b[ct * 16 + c];
    obv[ct] = out_b[ct * 16 + c]; fbv[ct] = ffn_b[ct * 16 + c];
  }
  float o1[4][4];
#pragma unroll
  for (int ct = 0; ct < 4; ct++)
#pragma unroll
    for (int r = 0; r < 4; r++)
      o1[ct][r] = x[((size_t)b * NN + i0 + 4 * g + r) * EE + ct * 16 + c] +
                  acc[ct][r] / trow[r] + obv[ct];
  // LN1
  float h1[4][4];
#pragma unroll
  for (int r = 0; r < 4; r++) {
    float s = o1[0][r] + o1[1][r] + o1[2][r] + o1[3][r];
    float s2 = o1[0][r] * o1[0][r] + o1[1][r] * o1[1][r] +
               o1[2][r] * o1[2][r] + o1[3][r] * o1[3][r];
#pragma unroll
    for (int xm = 1; xm < 16; xm <<= 1) { s += __shfl_xor(s, xm); s2 += __shfl_xor(s2, xm); }
    float mean = s * (1.f / 64.f);
    float var = s2 * (1.f / 64.f) - mean * mean;
    float rstd = rsqrtf(var + 1e-5f);
#pragma unroll
    for (int ct = 0; ct < 4; ct++)
      h1[ct][r] = (o1[ct][r] - mean) * rstd * gv[ct] + bvv[ct];
  }
#pragma unroll
  for (int ct = 0; ct < 4; ct++)
#pragma unroll
    for (int r = 0; r < 4; r++)
      *(unsigned short*)(hb + (4 * g + r) * 144 + ct * 32 + 2 * c) = f2bf(h1[ct][r]);
  asm volatile("s_waitcnt lgkmcnt(0)" ::: "memory");
  __builtin_amdgcn_sched_barrier(0);
  short8 hf0 = *(const short8*)(hb + c * 144 + g * 16);
  short8 hf1 = *(const short8*)(hb + c * 144 + 64 + g * 16);
  f32x4 a2[4];
#pragma unroll
  for (int ct = 0; ct < 4; ct++) {
    a2[ct] = (f32x4){0.f, 0.f, 0.f, 0.f};
    a2[ct] = MFMA16(hf0, *(const short8*)(ffnwb + (ct * 16 + c) * EE + g * 8), a2[ct]);
    a2[ct] = MFMA16(hf1, *(const short8*)(ffnwb + (ct * 16 + c) * EE + 32 + g * 8), a2[ct]);
  }
  float o3[4][4];
#pragma unroll
  for (int ct = 0; ct < 4; ct++)
#pragma unroll
    for (int r = 0; r < 4; r++) {
      float vv = a2[ct][r] + fbv[ct];
      float sp = fmaxf(vv, 0.f) + log1pf(expf(-fabsf(vv)));
      o3[ct][r] = o1[ct][r] + sp;
    }
#pragma unroll
  for (int r = 0; r < 4; r++) {
    float s = o3[0][r] + o3[1][r] + o3[2][r] + o3[3][r];
    float s2 = o3[0][r] * o3[0][r] + o3[1][r] * o3[1][r] +
               o3[2][r] * o3[2][r] + o3[3][r] * o3[3][r];
#pragma unroll
    for (int xm = 1; xm < 16; xm <<= 1) { s += __shfl_xor(s, xm); s2 += __shfl_xor(s2, xm); }
    float mean = s * (1.f / 64.f);
    float var = s2 * (1.f / 64.f) - mean * mean;
    float rstd = rsqrtf(var + 1e-5f);
#pragma unroll
    for (int ct = 0; ct < 4; ct++)
      out[((size_t)b * NN + i0 + 4 * g + r) * EE + ct * 16 + c] =
          (o3[ct][r] - mean) * rstd * gv[ct] + bvv[ct];
  }
}

// ---------------------------------------------------------------------------
extern "C" void kernel_launch(void* const* d_in, const int* in_sizes, int n_in,
                              void* d_out, int out_size, void* d_ws, size_t ws_size,
                              hipStream_t stream) {
  (void)in_sizes; (void)n_in; (void)out_size; (void)ws_size;
  const float* x = (const float*)d_in[0];
  const float* wts = (const float*)d_in[1];
  const float* ln_g = (const float*)d_in[2];
  const float* ln_b = (const float*)d_in[3];
  const float* wq_w = (const float*)d_in[4];
  const float* wq_b = (const float*)d_in[5];
  const float* wk_w = (const float*)d_in[6];
  const float* wk_b = (const float*)d_in[7];
  const float* wv_w = (const float*)d_in[8];
  const float* wv_b = (const float*)d_in[9];
  const float* mq_w = (const float*)d_in[10];
  const float* mq_b = (const float*)d_in[11];
  const float* mk_w = (const float*)d_in[12];
  const float* mk_b = (const float*)d_in[13];
  const float* out_w = (const float*)d_in[14];
  const float* out_b = (const float*)d_in[15];
  const float* ffn_w = (const float*)d_in[16];
  const float* ffn_b = (const float*)d_in[17];
  float* out = (float*)d_out;

  char* ws = (char*)d_ws;
  unsigned short* qb = (unsigned short*)(ws + 0);
  unsigned short* kb = (unsigned short*)(ws + 8388608);
  unsigned short* vt = (unsigned short*)(ws + 16777216);
  float* m1 = (float*)(ws + 25165824);
  float* l1 = (float*)(ws + 25690112);
  unsigned short* num = (unsigned short*)(ws + 26214400);
  float* tws = (float*)(ws + 42991616);
  unsigned short* wqc = (unsigned short*)(ws + 43122688);
  unsigned short* wkc = (unsigned short*)(ws + 43155456);
  unsigned short* wvc = (unsigned short*)(ws + 43188224);
  float* bqc = (float*)(ws + 43220992);
  float* bkc = (float*)(ws + 43222016);
  unsigned short* outwb = (unsigned short*)(ws + 43223040);
  unsigned short* ffnwb = (unsigned short*)(ws + 43255808);

  kprep<<<256, 128, 0, stream>>>(wq_w, wq_b, wk_w, wk_b, wv_w, mq_w, mq_b,
                                 mk_w, mk_b, out_w, ffn_w, wqc, bqc, wkc, bkc,
                                 wvc, outwb, ffnwb);
  kproj<<<256, 256, 0, stream>>>(x, ln_g, ln_b, wqc, bqc, wkc, bkc, wvc, wv_b,
                                 qb, kb, vt);
  kpass1<<<dim3(128, 2), 512, 0, stream>>>(qb, kb, wts, m1, l1);
  kpass2<<<dim3(128, 2), 512, 0, stream>>>(qb, kb, vt, wts, m1, l1, num, tws);
  kfinal<<<256, 256, 0, stream>>>(num, tws, x, outwb, out_b, ln_g, ln_b, ffnwb,
                                  ffn_b, out);
}